// Round 3
// baseline (604.647 us; speedup 1.0000x reference)
//
#include <hip/hip_runtime.h>
#include <math.h>

#define N_NODES 5000
#define E_EDGES 160000
#define H_HEADS 6
#define D_FEAT  64
#define IN_FEAT 131
#define HD      384          // H*D
#define NC4     (N_NODES/4)  // 1250
#define AGG_CAP 1024         // max edges staged in LDS per node (fallback path beyond)

// native clang vector type: valid operand for __builtin_nontemporal_* (HIP float4 class is not)
typedef float vf4 __attribute__((ext_vector_type(4)));

// ---------------- CSR build ----------------
__global__ void k_count(const int* __restrict__ dst, int* __restrict__ deg) {
    int e = blockIdx.x * blockDim.x + threadIdx.x;
    if (e < E_EDGES) atomicAdd(&deg[dst[e]], 1);
}

// single block, 1024 threads: exclusive scan of deg[0..N) -> row_ptr, zero deg (reused as cursor)
__global__ void k_scan(int* __restrict__ deg, int* __restrict__ row_ptr) {
    __shared__ int part[1024];
    const int T = 1024;
    int t = threadIdx.x;
    const int per = (N_NODES + T - 1) / T;   // 5
    int start = t * per;
    int s = 0;
    for (int i = 0; i < per; i++) {
        int idx = start + i;
        if (idx < N_NODES) s += deg[idx];
    }
    part[t] = s;
    __syncthreads();
    for (int off = 1; off < T; off <<= 1) {
        int v = (t >= off) ? part[t - off] : 0;
        __syncthreads();
        part[t] += v;
        __syncthreads();
    }
    int excl = (t == 0) ? 0 : part[t - 1];
    for (int i = 0; i < per; i++) {
        int idx = start + i;
        if (idx < N_NODES) {
            row_ptr[idx] = excl;
            excl += deg[idx];
            deg[idx] = 0;     // reset as fill cursor
        }
    }
    if (t == T - 1) row_ptr[N_NODES] = part[T - 1];
}

// store SOURCE NODE ID directly (edge identity never needed downstream)
__global__ void k_fill(const int* __restrict__ src, const int* __restrict__ dst,
                       const int* __restrict__ row_ptr,
                       int* __restrict__ cursor, int* __restrict__ csrc) {
    int e = blockIdx.x * blockDim.x + threadIdx.x;
    if (e < E_EDGES) {
        int d = dst[e];
        int p = atomicAdd(&cursor[d], 1);
        csrc[row_ptr[d] + p] = src[e];
    }
}

// ---------------- fp32 SGEMM, single-wave 32x32 tile: C[M,384] = A[M,K] @ W[K,384] ----
// grid (HD/32=12, ceil(M/32)); 64 threads (ONE wave) per block -> barriers are free,
// 1884 blocks give ~7 blocks/CU so LDS/VMEM latency is hidden by sibling waves.
__global__ __launch_bounds__(64, 8) void k_gemm(const float* __restrict__ A,
                                                const float* __restrict__ W,
                                                float* __restrict__ C, int M, int K) {
    const int BM = 32, BN = 32, BK = 32;
    __shared__ float As[BK][BM + 4];   // +4: keeps float4 alignment (144B stride)
    __shared__ float Bs[BK][BN + 4];
    int bx = blockIdx.x;          // n tile (0..11)
    int by = blockIdx.y;          // m tile
    int tid = threadIdx.x;        // 0..63
    int tx = tid & 7, ty = tid >> 3;      // 8x8 threads, each 4x4 outputs
    int rowBase = by * BM;
    int colBase = bx * BN;
    float acc[4][4] = {};
    const bool kvec = ((K & 3) == 0);     // layer0 K=131 -> guarded scalar A loads
    for (int k0 = 0; k0 < K; k0 += BK) {
        // stage A: 32 rows x 32 k. thread -> rows (tid>>3)+8i, k-chunk (tid&7)*4
#pragma unroll
        for (int i = 0; i < 4; i++) {
            int m = (tid >> 3) + 8 * i;
            int gr = rowBase + m;
            int gk = k0 + (tid & 7) * 4;
            float4 v = {0.f, 0.f, 0.f, 0.f};
            if (gr < M) {
                if (kvec && gk + 3 < K) {
                    v = *(const float4*)(A + (size_t)gr * K + gk);
                } else {
                    float* vv = (float*)&v;
#pragma unroll
                    for (int q = 0; q < 4; q++)
                        if (gk + q < K) vv[q] = A[(size_t)gr * K + gk + q];
                }
            }
            int kk = (tid & 7) * 4;
            As[kk + 0][m] = v.x;
            As[kk + 1][m] = v.y;
            As[kk + 2][m] = v.z;
            As[kk + 3][m] = v.w;
        }
        // stage B: 32 k x 32 n. thread -> k-rows (tid>>3)+8i, n-chunk (tid&7)*4
#pragma unroll
        for (int i = 0; i < 4; i++) {
            int kr = (tid >> 3) + 8 * i;
            int gk = k0 + kr;
            float4 v = {0.f, 0.f, 0.f, 0.f};
            if (gk < K) v = *(const float4*)(W + (size_t)gk * HD + colBase + (tid & 7) * 4);
            *(float4*)&Bs[kr][(tid & 7) * 4] = v;
        }
        __syncthreads();
#pragma unroll 8
        for (int k = 0; k < BK; k++) {
            float4 a = *(const float4*)&As[k][ty * 4];
            float4 b = *(const float4*)&Bs[k][tx * 4];
            const float* ap = (const float*)&a;
            const float* bp = (const float*)&b;
#pragma unroll
            for (int i = 0; i < 4; i++)
#pragma unroll
                for (int j = 0; j < 4; j++) acc[i][j] += ap[i] * bp[j];
        }
        __syncthreads();
    }
#pragma unroll
    for (int i = 0; i < 4; i++) {
        int gr = rowBase + ty * 4 + i;
        if (gr < M) {
            float4 v = {acc[i][0], acc[i][1], acc[i][2], acc[i][3]};
            *(float4*)(C + (size_t)gr * HD + colBase + tx * 4) = v;
        }
    }
}

// ---------------- el/er: per-(node,head) dot over D ----------------
__global__ void k_elr(const float* __restrict__ f, const float* __restrict__ al,
                      const float* __restrict__ ar, float* __restrict__ el,
                      float* __restrict__ er) {
    int wave = (blockIdx.x * blockDim.x + threadIdx.x) >> 6;
    int lane = threadIdx.x & 63;
    if (wave >= N_NODES * H_HEADS) return;
    int n = wave / H_HEADS, h = wave % H_HEADS;
    float v = f[n * HD + h * D_FEAT + lane];
    float pl = v * al[h * D_FEAT + lane];
    float pr = v * ar[h * D_FEAT + lane];
    for (int off = 32; off; off >>= 1) {
        pl += __shfl_down(pl, off);
        pr += __shfl_down(pr, off);
    }
    if (lane == 0) { el[wave] = pl; er[wave] = pr; }
}

// ---------------- per-dst softmax + weighted gather-sum (LDS-staged) ----------------
// s_x layout is [head][edge] (stride-1 in edge index): score/weight passes are
// conflict-free (lane i -> bank i%32, 2-way alias = free), gather pass is a
// same-address broadcast. The old [edge][head] layout was a 4-way bank conflict.
__global__ __launch_bounds__(384) void k_agg(const float* __restrict__ f,
                                             const float* __restrict__ el,
                                             const float* __restrict__ er,
                                             const float* __restrict__ bias,
                                             const int* __restrict__ row_ptr,
                                             const int* __restrict__ csrc,
                                             float* __restrict__ out, int activate) {
    __shared__ int   s_src[AGG_CAP];
    __shared__ float s_x[H_HEADS][AGG_CAP];
    __shared__ float sh_inv[H_HEADS];
    int node = blockIdx.x;
    int t = threadIdx.x;
    int h = t >> 6, lane = t & 63;
    int r0 = row_ptr[node], r1 = row_ptr[node + 1];
    int deg = r1 - r0;
    int dcap = deg < AGG_CAP ? deg : AGG_CAP;
    float er_h = er[node * H_HEADS + h];

    // stage src ids (all 384 threads)
    for (int i = t; i < dcap; i += 384) s_src[i] = csrc[r0 + i];
    __syncthreads();

    // per-head: compute leaky scores into LDS + running max (wave h, lanes over edges)
    float m = -1e30f;
    for (int i = lane; i < dcap; i += 64) {
        int s = s_src[i];
        float x = el[s * H_HEADS + h] + er_h;
        x = x >= 0.f ? x : 0.2f * x;
        s_x[h][i] = x;
        m = fmaxf(m, x);
    }
    for (int i = AGG_CAP + lane; i < deg; i += 64) {   // rare tail (deg > CAP)
        int s = csrc[r0 + i];
        float x = el[s * H_HEADS + h] + er_h;
        x = x >= 0.f ? x : 0.2f * x;
        m = fmaxf(m, x);
    }
    for (int off = 32; off; off >>= 1) m = fmaxf(m, __shfl_down(m, off));
    m = __shfl(m, 0);

    // sum of exp; overwrite s_x with unnormalized weight
    float ssum = 0.f;
    for (int i = lane; i < dcap; i += 64) {
        float w = __expf(s_x[h][i] - m);
        s_x[h][i] = w;
        ssum += w;
    }
    for (int i = AGG_CAP + lane; i < deg; i += 64) {
        int s = csrc[r0 + i];
        float x = el[s * H_HEADS + h] + er_h;
        x = x >= 0.f ? x : 0.2f * x;
        ssum += __expf(x - m);
    }
    for (int off = 32; off; off >>= 1) ssum += __shfl_down(ssum, off);
    if (lane == 0) sh_inv[h] = (ssum > 0.f) ? 1.f / ssum : 0.f;
    __syncthreads();
    float inv = sh_inv[h];

    // accumulate: thread (h,lane) sums w * f[src, h, lane]; 8 gathers in flight
    const float* fh = f + h * D_FEAT + lane;
    float acc = 0.f;
    int i = 0;
    int lim = dcap & ~7;
    for (; i < lim; i += 8) {
        int s0 = s_src[i + 0], s1 = s_src[i + 1], s2 = s_src[i + 2], s3 = s_src[i + 3];
        int s4 = s_src[i + 4], s5 = s_src[i + 5], s6 = s_src[i + 6], s7 = s_src[i + 7];
        float f0 = fh[(size_t)s0 * HD], f1 = fh[(size_t)s1 * HD];
        float f2 = fh[(size_t)s2 * HD], f3 = fh[(size_t)s3 * HD];
        float f4 = fh[(size_t)s4 * HD], f5 = fh[(size_t)s5 * HD];
        float f6 = fh[(size_t)s6 * HD], f7 = fh[(size_t)s7 * HD];
        acc += s_x[h][i + 0] * f0;
        acc += s_x[h][i + 1] * f1;
        acc += s_x[h][i + 2] * f2;
        acc += s_x[h][i + 3] * f3;
        acc += s_x[h][i + 4] * f4;
        acc += s_x[h][i + 5] * f5;
        acc += s_x[h][i + 6] * f6;
        acc += s_x[h][i + 7] * f7;
    }
    for (; i < dcap; i++) {
        acc += s_x[h][i] * fh[(size_t)s_src[i] * HD];
    }
    for (i = AGG_CAP; i < deg; i++) {                  // rare tail
        int s = csrc[r0 + i];
        float x = el[s * H_HEADS + h] + er_h;
        x = x >= 0.f ? x : 0.2f * x;
        acc += __expf(x - m) * fh[(size_t)s * HD];
    }
    float o = acc * inv + bias[h * D_FEAT + lane];
    if (activate) o = o > 0.f ? o : (__expf(o) - 1.f);
    out[node * HD + h * D_FEAT + lane] = o;
}

// ---------------- head-mean + two dots with pw ----------------
__global__ void k_embed(const float* __restrict__ h3, const float* __restrict__ pw,
                        float* __restrict__ s1, float* __restrict__ s2) {
    int wave = (blockIdx.x * blockDim.x + threadIdx.x) >> 6;
    int lane = threadIdx.x & 63;
    if (wave >= N_NODES) return;
    float s = 0.f;
#pragma unroll
    for (int hh = 0; hh < H_HEADS; hh++) s += h3[wave * HD + hh * D_FEAT + lane];
    s *= (1.f / 6.f);
    float p1 = s * pw[lane];
    float p2 = s * pw[D_FEAT + lane];
    for (int off = 32; off; off >>= 1) {
        p1 += __shfl_down(p1, off);
        p2 += __shfl_down(p2, off);
    }
    if (lane == 0) { s1[wave] = p1; s2[wave] = p2; }
}

// fast, branchless, numerically-stable tanh: t = exp(-2|z|) in (0,1],
// r = (1-t)/(1+t) in [0,1), result = copysign(r, z). |err| ~ 1e-7.
__device__ __forceinline__ float fast_tanh(float z) {
    float t = __expf(-2.f * fabsf(z));
    float r = (1.f - t) / (1.f + t);
    return copysignf(r, z);
}

// ---------------- pairwise tanh output ----------------
__global__ void k_pair(const vf4* __restrict__ dis, const float* __restrict__ s1,
                       const float* __restrict__ s2, const float* __restrict__ pw,
                       const float* __restrict__ pb, vf4* __restrict__ out) {
    const int total = N_NODES * NC4;
    float w = pw[2 * D_FEAT];
    float b = pb[0];
    for (int idx = blockIdx.x * blockDim.x + threadIdx.x; idx < total;
         idx += gridDim.x * blockDim.x) {
        int i = idx / NC4;
        int j4 = idx - i * NC4;
        vf4 dv = __builtin_nontemporal_load(&dis[idx]);   // read-once stream
        float base = s2[i] + b;
        int j = j4 * 4;
        vf4 o;
        o.x = fast_tanh(base + s1[j + 0] + dv.x * w);
        o.y = fast_tanh(base + s1[j + 1] + dv.y * w);
        o.z = fast_tanh(base + s1[j + 2] + dv.z * w);
        o.w = fast_tanh(base + s1[j + 3] + dv.w * w);
        __builtin_nontemporal_store(o, &out[idx]);        // write-once stream
    }
}

extern "C" void kernel_launch(void* const* d_in, const int* in_sizes, int n_in,
                              void* d_out, int out_size, void* d_ws, size_t ws_size,
                              hipStream_t stream) {
    const float* nfeats = (const float*)d_in[0];
    const float* dis    = (const float*)d_in[1];
    const int*   src    = (const int*)d_in[2];
    const int*   dst    = (const int*)d_in[3];
    const float* w[4]  = {(const float*)d_in[4],  (const float*)d_in[8],
                          (const float*)d_in[12], (const float*)d_in[16]};
    const float* al[4] = {(const float*)d_in[5],  (const float*)d_in[9],
                          (const float*)d_in[13], (const float*)d_in[17]};
    const float* ar[4] = {(const float*)d_in[6],  (const float*)d_in[10],
                          (const float*)d_in[14], (const float*)d_in[18]};
    const float* bs[4] = {(const float*)d_in[7],  (const float*)d_in[11],
                          (const float*)d_in[15], (const float*)d_in[19]};
    const float* pw = (const float*)d_in[20];
    const float* pb = (const float*)d_in[21];
    float* out = (float*)d_out;

    // workspace layout
    float* f    = (float*)d_ws;                 // N*HD
    float* hbuf = f + N_NODES * HD;             // N*HD
    float* el   = hbuf + N_NODES * HD;          // N*H
    float* er   = el + N_NODES * H_HEADS;       // N*H
    float* s1   = er + N_NODES * H_HEADS;       // N
    float* s2   = s1 + N_NODES;                 // N
    int* row_ptr = (int*)(s2 + N_NODES);        // N+1
    int* cursor  = row_ptr + (N_NODES + 1);     // N
    int* csrc    = cursor + N_NODES;            // E (source node id, grouped by dst)

    // CSR build (dst-indexed)
    (void)hipMemsetAsync(cursor, 0, N_NODES * sizeof(int), stream);
    k_count<<<(E_EDGES + 255) / 256, 256, 0, stream>>>(dst, cursor);
    k_scan<<<1, 1024, 0, stream>>>(cursor, row_ptr);
    k_fill<<<(E_EDGES + 255) / 256, 256, 0, stream>>>(src, dst, row_ptr, cursor, csrc);

    const float* hin = nfeats;
    for (int l = 0; l < 4; l++) {
        int K = (l == 0) ? IN_FEAT : HD;
        dim3 g(HD / 32, (N_NODES + 31) / 32);
        k_gemm<<<g, 64, 0, stream>>>(hin, w[l], f, N_NODES, K);
        k_elr<<<(N_NODES * H_HEADS + 3) / 4, 256, 0, stream>>>(f, al[l], ar[l], el, er);
        k_agg<<<N_NODES, 384, 0, stream>>>(f, el, er, bs[l], row_ptr, csrc, hbuf,
                                           (l < 3) ? 1 : 0);
        hin = hbuf;
    }
    k_embed<<<(N_NODES + 3) / 4, 256, 0, stream>>>(hbuf, pw, s1, s2);
    k_pair<<<4096, 256, 0, stream>>>((const vf4*)dis, s1, s2, pw, pb, (vf4*)out);
}

// Round 4
// 521.876 us; speedup vs baseline: 1.1586x; 1.1586x over previous
//
#include <hip/hip_runtime.h>
#include <math.h>

#define N_NODES 5000
#define E_EDGES 160000
#define H_HEADS 6
#define D_FEAT  64
#define IN_FEAT 131
#define HD      384          // H*D
#define NC4     (N_NODES/4)  // 1250
#define AGG_CAP 1024         // max edges staged in LDS per node (fallback path beyond)

// native clang vector type: valid operand for __builtin_nontemporal_* (HIP float4 class is not)
typedef float vf4 __attribute__((ext_vector_type(4)));

// ---------------- CSR build ----------------
__global__ void k_count(const int* __restrict__ dst, int* __restrict__ deg) {
    int e = blockIdx.x * blockDim.x + threadIdx.x;
    if (e < E_EDGES) atomicAdd(&deg[dst[e]], 1);
}

// single block, 1024 threads: exclusive scan of deg[0..N) -> row_ptr, zero deg (reused as cursor)
__global__ void k_scan(int* __restrict__ deg, int* __restrict__ row_ptr) {
    __shared__ int part[1024];
    const int T = 1024;
    int t = threadIdx.x;
    const int per = (N_NODES + T - 1) / T;   // 5
    int start = t * per;
    int s = 0;
    for (int i = 0; i < per; i++) {
        int idx = start + i;
        if (idx < N_NODES) s += deg[idx];
    }
    part[t] = s;
    __syncthreads();
    for (int off = 1; off < T; off <<= 1) {
        int v = (t >= off) ? part[t - off] : 0;
        __syncthreads();
        part[t] += v;
        __syncthreads();
    }
    int excl = (t == 0) ? 0 : part[t - 1];
    for (int i = 0; i < per; i++) {
        int idx = start + i;
        if (idx < N_NODES) {
            row_ptr[idx] = excl;
            excl += deg[idx];
            deg[idx] = 0;     // reset as fill cursor
        }
    }
    if (t == T - 1) row_ptr[N_NODES] = part[T - 1];
}

// store SOURCE NODE ID directly (edge identity never needed downstream)
__global__ void k_fill(const int* __restrict__ src, const int* __restrict__ dst,
                       const int* __restrict__ row_ptr,
                       int* __restrict__ cursor, int* __restrict__ csrc) {
    int e = blockIdx.x * blockDim.x + threadIdx.x;
    if (e < E_EDGES) {
        int d = dst[e];
        int p = atomicAdd(&cursor[d], 1);
        csrc[row_ptr[d] + p] = src[e];
    }
}

// ---------------- fp32 SGEMM, single-wave 32x32 tile: C[M,384] = A[M,K] @ W[K,384] ----
// One wave64 per block => NO __syncthreads needed at all (compiler lgkmcnt ordering
// suffices) => no vmcnt(0)/lgkmcnt(0) barrier drain. Register-prefetch double-buffer:
// tile t+1's 8 float4 global loads are issued before the 32 k-iter FMA block of tile t
// (~1024 VALU cycles) so L2/L3 latency (~500cy) is fully hidden. Grid-limited occupancy
// (1884 waves / 1024 SIMDs ~ 1.8 waves/SIMD), so per-wave ILP is the lever.
__global__ __launch_bounds__(64, 8) void k_gemm(const float* __restrict__ A,
                                                const float* __restrict__ W,
                                                float* __restrict__ C, int M, int K) {
    const int BM = 32, BN = 32, BK = 32;
    __shared__ float As[2][BK][BM + 4];   // +4: keeps float4 alignment (144B stride)
    __shared__ float Bs[2][BK][BN + 4];
    int bx = blockIdx.x;          // n tile (0..11)
    int by = blockIdx.y;          // m tile
    int tid = threadIdx.x;        // 0..63
    int tx = tid & 7, ty = tid >> 3;      // 8x8 threads, each 4x4 outputs
    int rowBase = by * BM;
    int colBase = bx * BN;
    const bool kvec = ((K & 3) == 0);     // layer0 K=131 -> guarded scalar A loads
    const int T = (K + BK - 1) / BK;
    float acc[4][4] = {};
    float4 pa[4], pb[4];                  // prefetch registers (32 VGPR)

    auto prefetch = [&](int t) {
        int k0 = t * BK;
#pragma unroll
        for (int i = 0; i < 4; i++) {
            int gr = rowBase + ty + 8 * i;
            int gk = k0 + tx * 4;
            float4 v = {0.f, 0.f, 0.f, 0.f};
            if (gr < M) {
                if (kvec && gk + 3 < K) {
                    v = *(const float4*)(A + (size_t)gr * K + gk);
                } else {
                    float* vv = (float*)&v;
#pragma unroll
                    for (int q = 0; q < 4; q++)
                        if (gk + q < K) vv[q] = A[(size_t)gr * K + gk + q];
                }
            }
            pa[i] = v;
            int gkr = k0 + ty + 8 * i;
            float4 w4 = {0.f, 0.f, 0.f, 0.f};
            if (gkr < K) w4 = *(const float4*)(W + (size_t)gkr * HD + colBase + tx * 4);
            pb[i] = w4;
        }
    };
    auto stage = [&](int buf) {
#pragma unroll
        for (int i = 0; i < 4; i++) {
            int m = ty + 8 * i;
            int kk = tx * 4;
            As[buf][kk + 0][m] = pa[i].x;    // transpose write (4-way bank alias, ~5% cost)
            As[buf][kk + 1][m] = pa[i].y;
            As[buf][kk + 2][m] = pa[i].z;
            As[buf][kk + 3][m] = pa[i].w;
            *(float4*)&Bs[buf][ty + 8 * i][tx * 4] = pb[i];
        }
    };

    prefetch(0);
    stage(0);
    for (int t = 0; t < T; t++) {
        int cur = t & 1;
        if (t + 1 < T) prefetch(t + 1);    // issue loads; consumed only after compute
#pragma unroll 8
        for (int k = 0; k < BK; k++) {
            float4 a = *(const float4*)&As[cur][k][ty * 4];   // broadcast across tx: conflict-free
            float4 b = *(const float4*)&Bs[cur][k][tx * 4];   // broadcast across ty: conflict-free
            const float* ap = (const float*)&a;
            const float* bp = (const float*)&b;
#pragma unroll
            for (int i = 0; i < 4; i++)
#pragma unroll
                for (int j = 0; j < 4; j++) acc[i][j] += ap[i] * bp[j];
        }
        if (t + 1 < T) stage(cur ^ 1);
    }
#pragma unroll
    for (int i = 0; i < 4; i++) {
        int gr = rowBase + ty * 4 + i;
        if (gr < M) {
            float4 v = {acc[i][0], acc[i][1], acc[i][2], acc[i][3]};
            *(float4*)(C + (size_t)gr * HD + colBase + tx * 4) = v;
        }
    }
}

// ---------------- el/er: per-(node,head) dot over D ----------------
__global__ void k_elr(const float* __restrict__ f, const float* __restrict__ al,
                      const float* __restrict__ ar, float* __restrict__ el,
                      float* __restrict__ er) {
    int wave = (blockIdx.x * blockDim.x + threadIdx.x) >> 6;
    int lane = threadIdx.x & 63;
    if (wave >= N_NODES * H_HEADS) return;
    int n = wave / H_HEADS, h = wave % H_HEADS;
    float v = f[n * HD + h * D_FEAT + lane];
    float pl = v * al[h * D_FEAT + lane];
    float pr = v * ar[h * D_FEAT + lane];
    for (int off = 32; off; off >>= 1) {
        pl += __shfl_down(pl, off);
        pr += __shfl_down(pr, off);
    }
    if (lane == 0) { el[wave] = pl; er[wave] = pr; }
}

// ---------------- per-dst softmax + weighted gather-sum (LDS-staged) ----------------
// s_x layout is [head][edge] (stride-1 in edge index): score/weight passes are
// conflict-free (lane i -> bank i%32, 2-way alias = free), gather pass is a
// same-address broadcast.
__global__ __launch_bounds__(384) void k_agg(const float* __restrict__ f,
                                             const float* __restrict__ el,
                                             const float* __restrict__ er,
                                             const float* __restrict__ bias,
                                             const int* __restrict__ row_ptr,
                                             const int* __restrict__ csrc,
                                             float* __restrict__ out, int activate) {
    __shared__ int   s_src[AGG_CAP];
    __shared__ float s_x[H_HEADS][AGG_CAP];
    __shared__ float sh_inv[H_HEADS];
    int node = blockIdx.x;
    int t = threadIdx.x;
    int h = t >> 6, lane = t & 63;
    int r0 = row_ptr[node], r1 = row_ptr[node + 1];
    int deg = r1 - r0;
    int dcap = deg < AGG_CAP ? deg : AGG_CAP;
    float er_h = er[node * H_HEADS + h];

    // stage src ids (all 384 threads)
    for (int i = t; i < dcap; i += 384) s_src[i] = csrc[r0 + i];
    __syncthreads();

    // per-head: compute leaky scores into LDS + running max (wave h, lanes over edges)
    float m = -1e30f;
    for (int i = lane; i < dcap; i += 64) {
        int s = s_src[i];
        float x = el[s * H_HEADS + h] + er_h;
        x = x >= 0.f ? x : 0.2f * x;
        s_x[h][i] = x;
        m = fmaxf(m, x);
    }
    for (int i = AGG_CAP + lane; i < deg; i += 64) {   // rare tail (deg > CAP)
        int s = csrc[r0 + i];
        float x = el[s * H_HEADS + h] + er_h;
        x = x >= 0.f ? x : 0.2f * x;
        m = fmaxf(m, x);
    }
    for (int off = 32; off; off >>= 1) m = fmaxf(m, __shfl_down(m, off));
    m = __shfl(m, 0);

    // sum of exp; overwrite s_x with unnormalized weight
    float ssum = 0.f;
    for (int i = lane; i < dcap; i += 64) {
        float w = __expf(s_x[h][i] - m);
        s_x[h][i] = w;
        ssum += w;
    }
    for (int i = AGG_CAP + lane; i < deg; i += 64) {
        int s = csrc[r0 + i];
        float x = el[s * H_HEADS + h] + er_h;
        x = x >= 0.f ? x : 0.2f * x;
        ssum += __expf(x - m);
    }
    for (int off = 32; off; off >>= 1) ssum += __shfl_down(ssum, off);
    if (lane == 0) sh_inv[h] = (ssum > 0.f) ? 1.f / ssum : 0.f;
    __syncthreads();
    float inv = sh_inv[h];

    // accumulate: thread (h,lane) sums w * f[src, h, lane]; 8 gathers in flight
    const float* fh = f + h * D_FEAT + lane;
    float acc = 0.f;
    int i = 0;
    int lim = dcap & ~7;
    for (; i < lim; i += 8) {
        int s0 = s_src[i + 0], s1 = s_src[i + 1], s2 = s_src[i + 2], s3 = s_src[i + 3];
        int s4 = s_src[i + 4], s5 = s_src[i + 5], s6 = s_src[i + 6], s7 = s_src[i + 7];
        float f0 = fh[(size_t)s0 * HD], f1 = fh[(size_t)s1 * HD];
        float f2 = fh[(size_t)s2 * HD], f3 = fh[(size_t)s3 * HD];
        float f4 = fh[(size_t)s4 * HD], f5 = fh[(size_t)s5 * HD];
        float f6 = fh[(size_t)s6 * HD], f7 = fh[(size_t)s7 * HD];
        acc += s_x[h][i + 0] * f0;
        acc += s_x[h][i + 1] * f1;
        acc += s_x[h][i + 2] * f2;
        acc += s_x[h][i + 3] * f3;
        acc += s_x[h][i + 4] * f4;
        acc += s_x[h][i + 5] * f5;
        acc += s_x[h][i + 6] * f6;
        acc += s_x[h][i + 7] * f7;
    }
    for (; i < dcap; i++) {
        acc += s_x[h][i] * fh[(size_t)s_src[i] * HD];
    }
    for (i = AGG_CAP; i < deg; i++) {                  // rare tail
        int s = csrc[r0 + i];
        float x = el[s * H_HEADS + h] + er_h;
        x = x >= 0.f ? x : 0.2f * x;
        acc += __expf(x - m) * fh[(size_t)s * HD];
    }
    float o = acc * inv + bias[h * D_FEAT + lane];
    if (activate) o = o > 0.f ? o : (__expf(o) - 1.f);
    out[node * HD + h * D_FEAT + lane] = o;
}

// ---------------- head-mean + two dots with pw ----------------
__global__ void k_embed(const float* __restrict__ h3, const float* __restrict__ pw,
                        float* __restrict__ s1, float* __restrict__ s2) {
    int wave = (blockIdx.x * blockDim.x + threadIdx.x) >> 6;
    int lane = threadIdx.x & 63;
    if (wave >= N_NODES) return;
    float s = 0.f;
#pragma unroll
    for (int hh = 0; hh < H_HEADS; hh++) s += h3[wave * HD + hh * D_FEAT + lane];
    s *= (1.f / 6.f);
    float p1 = s * pw[lane];
    float p2 = s * pw[D_FEAT + lane];
    for (int off = 32; off; off >>= 1) {
        p1 += __shfl_down(p1, off);
        p2 += __shfl_down(p2, off);
    }
    if (lane == 0) { s1[wave] = p1; s2[wave] = p2; }
}

// fast, branchless, numerically-stable tanh: t = exp(-2|z|) in (0,1],
// r = (1-t)/(1+t) in [0,1), result = copysign(r, z). |err| ~ 1e-7.
__device__ __forceinline__ float fast_tanh(float z) {
    float t = __expf(-2.f * fabsf(z));
    float r = (1.f - t) / (1.f + t);
    return copysignf(r, z);
}

// ---------------- pairwise tanh output ----------------
__global__ void k_pair(const vf4* __restrict__ dis, const float* __restrict__ s1,
                       const float* __restrict__ s2, const float* __restrict__ pw,
                       const float* __restrict__ pb, vf4* __restrict__ out) {
    const int total = N_NODES * NC4;
    float w = pw[2 * D_FEAT];
    float b = pb[0];
    for (int idx = blockIdx.x * blockDim.x + threadIdx.x; idx < total;
         idx += gridDim.x * blockDim.x) {
        int i = idx / NC4;
        int j4 = idx - i * NC4;
        vf4 dv = __builtin_nontemporal_load(&dis[idx]);   // read-once stream
        float base = s2[i] + b;
        int j = j4 * 4;
        vf4 o;
        o.x = fast_tanh(base + s1[j + 0] + dv.x * w);
        o.y = fast_tanh(base + s1[j + 1] + dv.y * w);
        o.z = fast_tanh(base + s1[j + 2] + dv.z * w);
        o.w = fast_tanh(base + s1[j + 3] + dv.w * w);
        __builtin_nontemporal_store(o, &out[idx]);        // write-once stream
    }
}

extern "C" void kernel_launch(void* const* d_in, const int* in_sizes, int n_in,
                              void* d_out, int out_size, void* d_ws, size_t ws_size,
                              hipStream_t stream) {
    const float* nfeats = (const float*)d_in[0];
    const float* dis    = (const float*)d_in[1];
    const int*   src    = (const int*)d_in[2];
    const int*   dst    = (const int*)d_in[3];
    const float* w[4]  = {(const float*)d_in[4],  (const float*)d_in[8],
                          (const float*)d_in[12], (const float*)d_in[16]};
    const float* al[4] = {(const float*)d_in[5],  (const float*)d_in[9],
                          (const float*)d_in[13], (const float*)d_in[17]};
    const float* ar[4] = {(const float*)d_in[6],  (const float*)d_in[10],
                          (const float*)d_in[14], (const float*)d_in[18]};
    const float* bs[4] = {(const float*)d_in[7],  (const float*)d_in[11],
                          (const float*)d_in[15], (const float*)d_in[19]};
    const float* pw = (const float*)d_in[20];
    const float* pb = (const float*)d_in[21];
    float* out = (float*)d_out;

    // workspace layout
    float* f    = (float*)d_ws;                 // N*HD
    float* hbuf = f + N_NODES * HD;             // N*HD
    float* el   = hbuf + N_NODES * HD;          // N*H
    float* er   = el + N_NODES * H_HEADS;       // N*H
    float* s1   = er + N_NODES * H_HEADS;       // N
    float* s2   = s1 + N_NODES;                 // N
    int* row_ptr = (int*)(s2 + N_NODES);        // N+1
    int* cursor  = row_ptr + (N_NODES + 1);     // N
    int* csrc    = cursor + N_NODES;            // E (source node id, grouped by dst)

    // CSR build (dst-indexed)
    (void)hipMemsetAsync(cursor, 0, N_NODES * sizeof(int), stream);
    k_count<<<(E_EDGES + 255) / 256, 256, 0, stream>>>(dst, cursor);
    k_scan<<<1, 1024, 0, stream>>>(cursor, row_ptr);
    k_fill<<<(E_EDGES + 255) / 256, 256, 0, stream>>>(src, dst, row_ptr, cursor, csrc);

    const float* hin = nfeats;
    for (int l = 0; l < 4; l++) {
        int K = (l == 0) ? IN_FEAT : HD;
        dim3 g(HD / 32, (N_NODES + 31) / 32);
        k_gemm<<<g, 64, 0, stream>>>(hin, w[l], f, N_NODES, K);
        k_elr<<<(N_NODES * H_HEADS + 3) / 4, 256, 0, stream>>>(f, al[l], ar[l], el, er);
        k_agg<<<N_NODES, 384, 0, stream>>>(f, el, er, bs[l], row_ptr, csrc, hbuf,
                                           (l < 3) ? 1 : 0);
        hin = hbuf;
    }
    k_embed<<<(N_NODES + 3) / 4, 256, 0, stream>>>(hbuf, pw, s1, s2);
    k_pair<<<4096, 256, 0, stream>>>((const vf4*)dis, s1, s2, pw, pb, (vf4*)out);
}

// Round 5
// 501.671 us; speedup vs baseline: 1.2053x; 1.0403x over previous
//
#include <hip/hip_runtime.h>
#include <math.h>

#define N_NODES 5000
#define E_EDGES 160000
#define H_HEADS 6
#define D_FEAT  64
#define IN_FEAT 131
#define HD      384          // H*D
#define NC4     (N_NODES/4)  // 1250
#define AGG_CAP 1024         // max edges staged in LDS per node (fallback path beyond)
#define MPAD    5024         // 157 row-blocks * 32 rows (zero-padded tail)
#define KP0     160          // layer0 K=131 padded to multiple of 32

// native clang vector types
typedef float vf4   __attribute__((ext_vector_type(4)));
typedef float f32x4 __attribute__((ext_vector_type(4)));
typedef _Float16 h16;
typedef _Float16 half8 __attribute__((ext_vector_type(8)));

// ---------------- CSR build ----------------
__global__ void k_count(const int* __restrict__ dst, int* __restrict__ deg) {
    int e = blockIdx.x * blockDim.x + threadIdx.x;
    if (e < E_EDGES) atomicAdd(&deg[dst[e]], 1);
}

__global__ void k_scan(int* __restrict__ deg, int* __restrict__ row_ptr) {
    __shared__ int part[1024];
    const int T = 1024;
    int t = threadIdx.x;
    const int per = (N_NODES + T - 1) / T;   // 5
    int start = t * per;
    int s = 0;
    for (int i = 0; i < per; i++) {
        int idx = start + i;
        if (idx < N_NODES) s += deg[idx];
    }
    part[t] = s;
    __syncthreads();
    for (int off = 1; off < T; off <<= 1) {
        int v = (t >= off) ? part[t - off] : 0;
        __syncthreads();
        part[t] += v;
        __syncthreads();
    }
    int excl = (t == 0) ? 0 : part[t - 1];
    for (int i = 0; i < per; i++) {
        int idx = start + i;
        if (idx < N_NODES) {
            row_ptr[idx] = excl;
            excl += deg[idx];
            deg[idx] = 0;     // reset as fill cursor
        }
    }
    if (t == T - 1) row_ptr[N_NODES] = part[T - 1];
}

__global__ void k_fill(const int* __restrict__ src, const int* __restrict__ dst,
                       const int* __restrict__ row_ptr,
                       int* __restrict__ cursor, int* __restrict__ csrc) {
    int e = blockIdx.x * blockDim.x + threadIdx.x;
    if (e < E_EDGES) {
        int d = dst[e];
        int p = atomicAdd(&cursor[d], 1);
        csrc[row_ptr[d] + p] = src[e];
    }
}

// ---------------- fp32 -> f16 hi/lo split conversions ----------------
// layer0 input: nfeats [N][131] -> A0hi/A0lo [MPAD][KP0], zero-padded
__global__ void k_cvt_a0(const float* __restrict__ A, h16* __restrict__ hi,
                         h16* __restrict__ lo) {
    int idx = blockIdx.x * blockDim.x + threadIdx.x;
    if (idx >= MPAD * KP0) return;
    int r = idx / KP0, k = idx - r * KP0;
    float v = (r < N_NODES && k < IN_FEAT) ? A[r * IN_FEAT + k] : 0.f;
    h16 h = (h16)v;
    hi[idx] = h;
    lo[idx] = (h16)(v - (float)h);
}

// W [K][384] -> Wt hi/lo [384][KP] (transpose + split), zero-padded in k
__global__ void k_cvt_w(const float* __restrict__ W, h16* __restrict__ hi,
                        h16* __restrict__ lo, int K, int KP) {
    int idx = blockIdx.x * blockDim.x + threadIdx.x;
    if (idx >= HD * KP) return;
    int n = idx / KP, k = idx - n * KP;
    float v = (k < K) ? W[(size_t)k * HD + n] : 0.f;
    h16 h = (h16)v;
    hi[idx] = h;
    lo[idx] = (h16)(v - (float)h);
}

// ---------------- MFMA GEMM (f16 hi/lo x3 split ~= fp32) + fused el/er ------
// One wave per block. Wave tile: 32 rows x 64 cols (= exactly head h=blockIdx.x).
// acc[m][t]: m in {0,1} 16-row halves, t in {0..3} 16-col tiles.
// mfma_f32_16x16x32_f16: A row = lane&15, B col = lane&15, k-chunk by lane>>4
// (any common k-permutation between A and B cancels in the dot product).
// C/D: col = lane&15, row = (lane>>4)*4 + reg  [m89-verified].
// Epilogue computes el/er (dot of produced f-tile with al/ar over the head's 64
// cols) via 16-lane shfl_xor reduction -> k_elr kernel eliminated.
__global__ __launch_bounds__(64, 2) void k_gemm_mfma(
        const h16* __restrict__ Ahi, const h16* __restrict__ Alo,
        const h16* __restrict__ Wthi, const h16* __restrict__ Wtlo,
        const float* __restrict__ al, const float* __restrict__ ar,
        float* __restrict__ C, float* __restrict__ el, float* __restrict__ er,
        int KP) {
    int lane = threadIdx.x;          // 0..63
    int h = blockIdx.x;              // head / 64-col block (0..5)
    int rb = blockIdx.y * 32;
    int cb = h * 64;
    int l15 = lane & 15, lg = lane >> 4;
    f32x4 acc[2][4] = {};

    const h16* a0h = Ahi + (size_t)(rb + l15) * KP + (lg << 3);
    const h16* a0l = Alo + (size_t)(rb + l15) * KP + (lg << 3);
    const h16* a1h = a0h + (size_t)16 * KP;
    const h16* a1l = a0l + (size_t)16 * KP;
    const h16* bh = Wthi + (size_t)(cb + l15) * KP + (lg << 3);
    const h16* bl = Wtlo + (size_t)(cb + l15) * KP + (lg << 3);

#pragma unroll 2
    for (int k0 = 0; k0 < KP; k0 += 32) {
        half8 A0h = *(const half8*)(a0h + k0);
        half8 A0l = *(const half8*)(a0l + k0);
        half8 A1h = *(const half8*)(a1h + k0);
        half8 A1l = *(const half8*)(a1l + k0);
#pragma unroll
        for (int t = 0; t < 4; t++) {
            half8 Bh = *(const half8*)(bh + (size_t)t * 16 * KP + k0);
            half8 Bl = *(const half8*)(bl + (size_t)t * 16 * KP + k0);
            acc[0][t] = __builtin_amdgcn_mfma_f32_16x16x32_f16(A0h, Bh, acc[0][t], 0, 0, 0);
            acc[0][t] = __builtin_amdgcn_mfma_f32_16x16x32_f16(A0l, Bh, acc[0][t], 0, 0, 0);
            acc[0][t] = __builtin_amdgcn_mfma_f32_16x16x32_f16(A0h, Bl, acc[0][t], 0, 0, 0);
            acc[1][t] = __builtin_amdgcn_mfma_f32_16x16x32_f16(A1h, Bh, acc[1][t], 0, 0, 0);
            acc[1][t] = __builtin_amdgcn_mfma_f32_16x16x32_f16(A1l, Bh, acc[1][t], 0, 0, 0);
            acc[1][t] = __builtin_amdgcn_mfma_f32_16x16x32_f16(A1h, Bl, acc[1][t], 0, 0, 0);
        }
    }

    float alv[4], arv[4];
#pragma unroll
    for (int t = 0; t < 4; t++) {
        alv[t] = al[h * D_FEAT + t * 16 + l15];
        arv[t] = ar[h * D_FEAT + t * 16 + l15];
    }
#pragma unroll
    for (int m = 0; m < 2; m++) {
#pragma unroll
        for (int r = 0; r < 4; r++) {
            int grow = rb + m * 16 + lg * 4 + r;
            float sl = 0.f, sr = 0.f;
#pragma unroll
            for (int t = 0; t < 4; t++) {
                float v = acc[m][t][r];
                if (grow < N_NODES) C[(size_t)grow * HD + cb + t * 16 + l15] = v;
                sl += v * alv[t];
                sr += v * arv[t];
            }
#pragma unroll
            for (int off = 1; off < 16; off <<= 1) {
                sl += __shfl_xor(sl, off);
                sr += __shfl_xor(sr, off);
            }
            if (l15 == 0 && grow < N_NODES) {
                el[grow * H_HEADS + h] = sl;
                er[grow * H_HEADS + h] = sr;
            }
        }
    }
}

// ---------------- per-dst softmax + weighted gather-sum (LDS-staged) ----------------
// s_x layout [head][edge]: stride-1, conflict-free. Epilogue also emits the f16
// hi/lo split of the output (next layer's GEMM A operand) - fuses the cvt pass.
__global__ __launch_bounds__(384) void k_agg(const float* __restrict__ f,
                                             const float* __restrict__ el,
                                             const float* __restrict__ er,
                                             const float* __restrict__ bias,
                                             const int* __restrict__ row_ptr,
                                             const int* __restrict__ csrc,
                                             float* __restrict__ out, int activate,
                                             h16* __restrict__ nhi,
                                             h16* __restrict__ nlo) {
    __shared__ int   s_src[AGG_CAP];
    __shared__ float s_x[H_HEADS][AGG_CAP];
    __shared__ float sh_inv[H_HEADS];
    int node = blockIdx.x;
    int t = threadIdx.x;
    int h = t >> 6, lane = t & 63;
    int r0 = row_ptr[node], r1 = row_ptr[node + 1];
    int deg = r1 - r0;
    int dcap = deg < AGG_CAP ? deg : AGG_CAP;
    float er_h = er[node * H_HEADS + h];

    for (int i = t; i < dcap; i += 384) s_src[i] = csrc[r0 + i];
    __syncthreads();

    float m = -1e30f;
    for (int i = lane; i < dcap; i += 64) {
        int s = s_src[i];
        float x = el[s * H_HEADS + h] + er_h;
        x = x >= 0.f ? x : 0.2f * x;
        s_x[h][i] = x;
        m = fmaxf(m, x);
    }
    for (int i = AGG_CAP + lane; i < deg; i += 64) {   // rare tail (deg > CAP)
        int s = csrc[r0 + i];
        float x = el[s * H_HEADS + h] + er_h;
        x = x >= 0.f ? x : 0.2f * x;
        m = fmaxf(m, x);
    }
    for (int off = 32; off; off >>= 1) m = fmaxf(m, __shfl_down(m, off));
    m = __shfl(m, 0);

    float ssum = 0.f;
    for (int i = lane; i < dcap; i += 64) {
        float w = __expf(s_x[h][i] - m);
        s_x[h][i] = w;
        ssum += w;
    }
    for (int i = AGG_CAP + lane; i < deg; i += 64) {
        int s = csrc[r0 + i];
        float x = el[s * H_HEADS + h] + er_h;
        x = x >= 0.f ? x : 0.2f * x;
        ssum += __expf(x - m);
    }
    for (int off = 32; off; off >>= 1) ssum += __shfl_down(ssum, off);
    if (lane == 0) sh_inv[h] = (ssum > 0.f) ? 1.f / ssum : 0.f;
    __syncthreads();
    float inv = sh_inv[h];

    const float* fh = f + h * D_FEAT + lane;
    float acc = 0.f;
    int i = 0;
    int lim = dcap & ~7;
    for (; i < lim; i += 8) {
        int s0 = s_src[i + 0], s1 = s_src[i + 1], s2 = s_src[i + 2], s3 = s_src[i + 3];
        int s4 = s_src[i + 4], s5 = s_src[i + 5], s6 = s_src[i + 6], s7 = s_src[i + 7];
        float f0 = fh[(size_t)s0 * HD], f1 = fh[(size_t)s1 * HD];
        float f2 = fh[(size_t)s2 * HD], f3 = fh[(size_t)s3 * HD];
        float f4 = fh[(size_t)s4 * HD], f5 = fh[(size_t)s5 * HD];
        float f6 = fh[(size_t)s6 * HD], f7 = fh[(size_t)s7 * HD];
        acc += s_x[h][i + 0] * f0;
        acc += s_x[h][i + 1] * f1;
        acc += s_x[h][i + 2] * f2;
        acc += s_x[h][i + 3] * f3;
        acc += s_x[h][i + 4] * f4;
        acc += s_x[h][i + 5] * f5;
        acc += s_x[h][i + 6] * f6;
        acc += s_x[h][i + 7] * f7;
    }
    for (; i < dcap; i++) {
        acc += s_x[h][i] * fh[(size_t)s_src[i] * HD];
    }
    for (i = AGG_CAP; i < deg; i++) {                  // rare tail
        int s = csrc[r0 + i];
        float x = el[s * H_HEADS + h] + er_h;
        x = x >= 0.f ? x : 0.2f * x;
        acc += __expf(x - m) * fh[(size_t)s * HD];
    }
    float o = acc * inv + bias[h * D_FEAT + lane];
    if (activate) o = o > 0.f ? o : (__expf(o) - 1.f);
    int oi = node * HD + h * D_FEAT + lane;
    out[oi] = o;
    if (nhi) {                        // fused f16 hi/lo split for next layer's GEMM
        h16 oh = (h16)o;
        nhi[oi] = oh;
        nlo[oi] = (h16)(o - (float)oh);
    }
}

// ---------------- head-mean + two dots with pw ----------------
__global__ void k_embed(const float* __restrict__ h3, const float* __restrict__ pw,
                        float* __restrict__ s1, float* __restrict__ s2) {
    int wave = (blockIdx.x * blockDim.x + threadIdx.x) >> 6;
    int lane = threadIdx.x & 63;
    if (wave >= N_NODES) return;
    float s = 0.f;
#pragma unroll
    for (int hh = 0; hh < H_HEADS; hh++) s += h3[wave * HD + hh * D_FEAT + lane];
    s *= (1.f / 6.f);
    float p1 = s * pw[lane];
    float p2 = s * pw[D_FEAT + lane];
    for (int off = 32; off; off >>= 1) {
        p1 += __shfl_down(p1, off);
        p2 += __shfl_down(p2, off);
    }
    if (lane == 0) { s1[wave] = p1; s2[wave] = p2; }
}

// fast, branchless, numerically-stable tanh
__device__ __forceinline__ float fast_tanh(float z) {
    float t = __expf(-2.f * fabsf(z));
    float r = (1.f - t) / (1.f + t);
    return copysignf(r, z);
}

// ---------------- pairwise tanh output ----------------
__global__ void k_pair(const vf4* __restrict__ dis, const float* __restrict__ s1,
                       const float* __restrict__ s2, const float* __restrict__ pw,
                       const float* __restrict__ pb, vf4* __restrict__ out) {
    const int total = N_NODES * NC4;
    float w = pw[2 * D_FEAT];
    float b = pb[0];
    for (int idx = blockIdx.x * blockDim.x + threadIdx.x; idx < total;
         idx += gridDim.x * blockDim.x) {
        int i = idx / NC4;
        int j4 = idx - i * NC4;
        vf4 dv = __builtin_nontemporal_load(&dis[idx]);   // read-once stream
        float base = s2[i] + b;
        int j = j4 * 4;
        vf4 o;
        o.x = fast_tanh(base + s1[j + 0] + dv.x * w);
        o.y = fast_tanh(base + s1[j + 1] + dv.y * w);
        o.z = fast_tanh(base + s1[j + 2] + dv.z * w);
        o.w = fast_tanh(base + s1[j + 3] + dv.w * w);
        __builtin_nontemporal_store(o, &out[idx]);        // write-once stream
    }
}

extern "C" void kernel_launch(void* const* d_in, const int* in_sizes, int n_in,
                              void* d_out, int out_size, void* d_ws, size_t ws_size,
                              hipStream_t stream) {
    const float* nfeats = (const float*)d_in[0];
    const float* dis    = (const float*)d_in[1];
    const int*   src    = (const int*)d_in[2];
    const int*   dst    = (const int*)d_in[3];
    const float* w[4]  = {(const float*)d_in[4],  (const float*)d_in[8],
                          (const float*)d_in[12], (const float*)d_in[16]};
    const float* al[4] = {(const float*)d_in[5],  (const float*)d_in[9],
                          (const float*)d_in[13], (const float*)d_in[17]};
    const float* ar[4] = {(const float*)d_in[6],  (const float*)d_in[10],
                          (const float*)d_in[14], (const float*)d_in[18]};
    const float* bs[4] = {(const float*)d_in[7],  (const float*)d_in[11],
                          (const float*)d_in[15], (const float*)d_in[19]};
    const float* pw = (const float*)d_in[20];
    const float* pb = (const float*)d_in[21];
    float* out = (float*)d_out;

    // workspace layout
    float* f    = (float*)d_ws;                 // N*HD
    float* hbuf = f + N_NODES * HD;             // N*HD
    float* el   = hbuf + N_NODES * HD;          // N*H
    float* er   = el + N_NODES * H_HEADS;       // N*H
    float* s1   = er + N_NODES * H_HEADS;       // N
    float* s2   = s1 + N_NODES;                 // N
    int* row_ptr = (int*)(s2 + N_NODES);        // N+1
    int* cursor  = row_ptr + (N_NODES + 1);     // N
    int* csrc    = cursor + N_NODES;            // E
    uintptr_t p = (uintptr_t)(csrc + E_EDGES);
    p = (p + 15) & ~(uintptr_t)15;
    h16* A0hi = (h16*)p;                        // MPAD*KP0
    h16* A0lo = A0hi + (size_t)MPAD * KP0;
    h16* Athi = A0lo + (size_t)MPAD * KP0;      // MPAD*HD (layers 1-3 input)
    h16* Atlo = Athi + (size_t)MPAD * HD;
    h16* Wthi = Atlo + (size_t)MPAD * HD;       // HD*HD (per-layer, reused)
    h16* Wtlo = Wthi + (size_t)HD * HD;

    // CSR build (dst-indexed)
    (void)hipMemsetAsync(cursor, 0, N_NODES * sizeof(int), stream);
    k_count<<<(E_EDGES + 255) / 256, 256, 0, stream>>>(dst, cursor);
    k_scan<<<1, 1024, 0, stream>>>(cursor, row_ptr);
    k_fill<<<(E_EDGES + 255) / 256, 256, 0, stream>>>(src, dst, row_ptr, cursor, csrc);

    // zero the padded tail rows of the layer1-3 A buffers (agg writes only <N rows)
    (void)hipMemsetAsync(Athi + (size_t)N_NODES * HD, 0,
                         (size_t)(MPAD - N_NODES) * HD * sizeof(h16), stream);
    (void)hipMemsetAsync(Atlo + (size_t)N_NODES * HD, 0,
                         (size_t)(MPAD - N_NODES) * HD * sizeof(h16), stream);

    dim3 gg(H_HEADS, (N_NODES + 31) / 32);      // (6, 157)

    // layer 0
    k_cvt_a0<<<(MPAD * KP0 + 255) / 256, 256, 0, stream>>>(nfeats, A0hi, A0lo);
    k_cvt_w<<<(HD * KP0 + 255) / 256, 256, 0, stream>>>(w[0], Wthi, Wtlo, IN_FEAT, KP0);
    k_gemm_mfma<<<gg, 64, 0, stream>>>(A0hi, A0lo, Wthi, Wtlo, al[0], ar[0],
                                       f, el, er, KP0);
    k_agg<<<N_NODES, 384, 0, stream>>>(f, el, er, bs[0], row_ptr, csrc, hbuf, 1,
                                       Athi, Atlo);
    // layers 1..3
    for (int l = 1; l < 4; l++) {
        k_cvt_w<<<(HD * HD + 255) / 256, 256, 0, stream>>>(w[l], Wthi, Wtlo, HD, HD);
        k_gemm_mfma<<<gg, 64, 0, stream>>>(Athi, Atlo, Wthi, Wtlo, al[l], ar[l],
                                           f, el, er, HD);
        k_agg<<<N_NODES, 384, 0, stream>>>(f, el, er, bs[l], row_ptr, csrc, hbuf,
                                           (l < 3) ? 1 : 0,
                                           (l < 3) ? Athi : (h16*)nullptr,
                                           (l < 3) ? Atlo : (h16*)nullptr);
    }
    k_embed<<<(N_NODES + 3) / 4, 256, 0, stream>>>(hbuf, pw, s1, s2);
    k_pair<<<4096, 256, 0, stream>>>((const vf4*)dis, s1, s2, pw, pb, (vf4*)out);
}